// Round 1
// baseline (3282.095 us; speedup 1.0000x reference)
//
#include <hip/hip_runtime.h>
#include <stdint.h>

// ---- problem constants ----
#define T_TOK 8192
#define H_DIM 2048
#define DFF_D 8192
#define NEXP  8

// ---- gemm tiling ----
#define CHUNK 8704   // slots per gemm chunk; 2 chunks cover worst case 16384
#define BM 128
#define BN 128
#define BK 64

typedef __bf16 bf16x8 __attribute__((ext_vector_type(8)));
typedef float  f32x4  __attribute__((ext_vector_type(4)));

__device__ __forceinline__ void async_ld16(const void* g, void* l) {
  __builtin_amdgcn_global_load_lds(
      (const __attribute__((address_space(1))) unsigned int*)g,
      (__attribute__((address_space(3))) unsigned int*)l, 16, 0, 0);
}

__device__ __forceinline__ unsigned short f2bf(float f) {
  union { float f; unsigned u; } v; v.f = f;
  unsigned u = v.u;
  u += 0x7fffu + ((u >> 16) & 1u);   // round-to-nearest-even
  return (unsigned short)(u >> 16);
}

// ---------------- router: logits (fp32, exact) + softmax/top2 + x->bf16 ----------------
__global__ void router_kernel(const float* __restrict__ x, const float* __restrict__ wg,
                              float* __restrict__ logits, unsigned short* __restrict__ x_bf,
                              int* __restrict__ topk_idx, float* __restrict__ topk_w,
                              int* __restrict__ counts)
{
  const int t = blockIdx.x;
  const int lane = threadIdx.x;      // 64
  const float* xr = x + (size_t)t * H_DIM;
  unsigned short* xbr = x_bf + (size_t)t * H_DIM;
  float acc[NEXP];
#pragma unroll
  for (int e = 0; e < NEXP; ++e) acc[e] = 0.f;
#pragma unroll
  for (int j = 0; j < H_DIM / 256; ++j) {
    const int h = j * 256 + lane * 4;
    const float4 xv = *(const float4*)(xr + h);
    union { unsigned short s[4]; uint2 u; } pk;
    pk.s[0] = f2bf(xv.x); pk.s[1] = f2bf(xv.y); pk.s[2] = f2bf(xv.z); pk.s[3] = f2bf(xv.w);
    *(uint2*)(xbr + h) = pk.u;
    const float xs[4] = {xv.x, xv.y, xv.z, xv.w};
#pragma unroll
    for (int q = 0; q < 4; ++q) {
      const float4 w0 = *(const float4*)(wg + (size_t)(h + q) * NEXP);
      const float4 w1v = *(const float4*)(wg + (size_t)(h + q) * NEXP + 4);
      acc[0] += xs[q] * w0.x;  acc[1] += xs[q] * w0.y;
      acc[2] += xs[q] * w0.z;  acc[3] += xs[q] * w0.w;
      acc[4] += xs[q] * w1v.x; acc[5] += xs[q] * w1v.y;
      acc[6] += xs[q] * w1v.z; acc[7] += xs[q] * w1v.w;
    }
  }
#pragma unroll
  for (int e = 0; e < NEXP; ++e)
#pragma unroll
    for (int off = 32; off > 0; off >>= 1)
      acc[e] += __shfl_xor(acc[e], off, 64);
  if (lane == 0) {
    float m = acc[0];
    for (int e = 1; e < NEXP; ++e) m = fmaxf(m, acc[e]);
    float p[NEXP], s = 0.f;
    for (int e = 0; e < NEXP; ++e) { p[e] = __expf(acc[e] - m); s += p[e]; }
    const float inv = 1.f / s;
    int i1 = 0; float b1 = p[0];
    for (int e = 1; e < NEXP; ++e) if (p[e] > b1) { b1 = p[e]; i1 = e; }   // ties: lowest idx
    int i2 = -1; float b2 = -1.f;
    for (int e = 0; e < NEXP; ++e) if (e != i1 && p[e] > b2) { b2 = p[e]; i2 = e; }
    for (int e = 0; e < NEXP; ++e) logits[(size_t)t * NEXP + e] = acc[e];
    topk_idx[t * 2]     = i1; topk_w[t * 2]     = b1 * inv;
    topk_idx[t * 2 + 1] = i2; topk_w[t * 2 + 1] = b2 * inv;
    atomicAdd(&counts[i1], 1);
    atomicAdd(&counts[i2], 1);
  }
}

// ---------------- scan: segment offsets + cursors ----------------
__global__ void scan_kernel(const int* __restrict__ counts, int* __restrict__ seg_off,
                            int* __restrict__ cursors)
{
  if (threadIdx.x == 0) {
    int off = 0;
    for (int e = 0; e < NEXP; ++e) { seg_off[e] = off; cursors[e] = off; off += counts[e]; }
  }
}

// ---------------- scatter: build expert-grouped slot lists ----------------
__global__ void scatter_kernel(const int* __restrict__ topk_idx, const float* __restrict__ topk_w,
                               int* __restrict__ cursors, int* __restrict__ slot_token,
                               float* __restrict__ slot_weight)
{
  int i = blockIdx.x * 256 + threadIdx.x;   // 0..16383
  if (i < T_TOK * 2) {
    int e = topk_idx[i];
    int pos = atomicAdd(&cursors[e], 1);
    slot_token[pos]  = i >> 1;
    slot_weight[pos] = topk_w[i];
  }
}

// ---------------- transpose + fp32->bf16:  in [R][C] fp32 -> out [C][R] bf16 ----------------
__global__ void transpose_cvt(const float* __restrict__ in, unsigned short* __restrict__ out,
                              int R, int C)
{
  __shared__ float tile[64][65];
  const int r0 = blockIdx.y * 64, c0 = blockIdx.x * 64;
  const int t = threadIdx.x;
  {
    const int rr = t >> 4, cc = (t & 15) * 4;
#pragma unroll
    for (int i = 0; i < 4; ++i) {
      const int r = rr + i * 16;
      const float4 v = *(const float4*)(in + (size_t)(r0 + r) * C + c0 + cc);
      tile[r][cc] = v.x; tile[r][cc + 1] = v.y; tile[r][cc + 2] = v.z; tile[r][cc + 3] = v.w;
    }
  }
  __syncthreads();
  const int c = t >> 2, rb = (t & 3) * 16;
  union { unsigned short s[16]; uint4 u[2]; } pk;
#pragma unroll
  for (int i = 0; i < 16; ++i) pk.s[i] = f2bf(tile[rb + i][c]);
  uint4* dst = (uint4*)(out + (size_t)(c0 + c) * R + r0 + rb);
  dst[0] = pk.u[0]; dst[1] = pk.u[1];
}

// ---------------- fused MoE GEMM ----------------
// MODE 0: hmid[slot,dff] = gelu(x_bf[token[slot]] @ w1t^T), KD=H_DIM, Bt=w1t [DFF][H]
// MODE 1: out[token] += weight[slot] * (hmid[slot] @ w2t^T), KD=DFF,  Bt=w2t [H][DFF]
// LDS layout: [row][64] bf16, 8-group XOR swizzle (slot s holds global kgroup s^(row&7))
// so global_load_lds (no padding possible) stays conflict-free on ds_read_b128 fragments.
template <int KD, int MODE>
__global__ __launch_bounds__(256, 2)
void moe_gemm(const unsigned short* __restrict__ Abase, const unsigned short* __restrict__ Bt,
              unsigned short* __restrict__ hmid, float* __restrict__ out,
              const int* __restrict__ counts, const int* __restrict__ seg_off,
              const int* __restrict__ slot_token, const float* __restrict__ slot_weight,
              int e, int c)
{
  const int cnt = counts[e];
  const int seg = seg_off[e];
  const int lr0 = c * CHUNK + blockIdx.x * BM;    // expert-local row base
  if (lr0 >= cnt) return;
  const int n0 = blockIdx.y * BN;

  __shared__ unsigned short Alds[BM * BK];  // 16 KB
  __shared__ unsigned short Blds[BN * BK];  // 16 KB
  __shared__ int   tokS[BM];
  __shared__ float wS[BM];

  const int tid = threadIdx.x;
  const int w = tid >> 6, lane = tid & 63;
  const int quad = lane >> 4, l16 = lane & 15;

  // staging sources: 4 issues each; thread covers (row=j*32+tid/8, lds kgroup=tid&7)
  const unsigned short* aSrc[4];
  const unsigned short* bSrc[4];
  {
    const int sgrp = tid & 7;
    const int rloc = tid >> 3;
#pragma unroll
    for (int j = 0; j < 4; ++j) {
      const int r = j * 32 + rloc;
      const int g = sgrp ^ (r & 7);          // global kgroup feeding lds slot sgrp
      if (MODE == 0) {
        const int lr = lr0 + r;
        const int tok = (lr < cnt) ? slot_token[seg + lr] : 0;
        aSrc[j] = Abase + (size_t)tok * H_DIM + g * 8;
      } else {
        const int lrow = blockIdx.x * BM + r;   // chunk-local hmid row
        aSrc[j] = Abase + (size_t)lrow * DFF_D + g * 8;
      }
      bSrc[j] = Bt + (size_t)(n0 + r) * KD + g * 8;
    }
  }

  f32x4 acc[4][4] = {};
  const int wm = w & 1, wn = w >> 1;

  for (int kt = 0; kt < KD / BK; ++kt) {
    {
      char* aL = (char*)Alds;
      char* bL = (char*)Blds;
      const int base = w * 1024;
#pragma unroll
      for (int j = 0; j < 4; ++j) {
        async_ld16(aSrc[j] + kt * BK, aL + j * 4096 + base);
        async_ld16(bSrc[j] + kt * BK, bL + j * 4096 + base);
      }
    }
    __syncthreads();   // compiler drains vmcnt before barrier

    bf16x8 afr[4][2], bfr[4][2];
#pragma unroll
    for (int mi = 0; mi < 4; ++mi) {
      const int m = wm * 64 + mi * 16 + l16;
#pragma unroll
      for (int h = 0; h < 2; ++h) {
        const int s = (h * 4 + quad) ^ (m & 7);
        afr[mi][h] = *(const bf16x8*)(Alds + m * BK + s * 8);
      }
    }
#pragma unroll
    for (int ni = 0; ni < 4; ++ni) {
      const int n = wn * 64 + ni * 16 + l16;
#pragma unroll
      for (int h = 0; h < 2; ++h) {
        const int s = (h * 4 + quad) ^ (n & 7);
        bfr[ni][h] = *(const bf16x8*)(Blds + n * BK + s * 8);
      }
    }
#pragma unroll
    for (int mi = 0; mi < 4; ++mi)
#pragma unroll
      for (int ni = 0; ni < 4; ++ni) {
        acc[mi][ni] = __builtin_amdgcn_mfma_f32_16x16x32_bf16(afr[mi][0], bfr[ni][0], acc[mi][ni], 0, 0, 0);
        acc[mi][ni] = __builtin_amdgcn_mfma_f32_16x16x32_bf16(afr[mi][1], bfr[ni][1], acc[mi][ni], 0, 0, 0);
      }
    __syncthreads();
  }

  if (MODE == 0) {
    // epilogue: fast tanh-gelu (gelu(v) = v * sigmoid(1.59577*(v + 0.044715 v^3))), store bf16
#pragma unroll
    for (int mi = 0; mi < 4; ++mi) {
      const int rowb = blockIdx.x * BM + wm * 64 + mi * 16 + quad * 4;
#pragma unroll
      for (int ni = 0; ni < 4; ++ni) {
        const int col = n0 + wn * 64 + ni * 16 + l16;
#pragma unroll
        for (int i = 0; i < 4; ++i) {
          const float v = acc[mi][ni][i];
          const float u = v * (1.5957691f + 0.07135481f * v * v);
          const float g = v / (1.f + __expf(-u));
          hmid[(size_t)(rowb + i) * DFF_D + col] = f2bf(g);
        }
      }
    }
  } else {
    if (tid < BM) {
      const int lr = lr0 + tid;
      const bool v = lr < cnt;
      tokS[tid] = v ? slot_token[seg + lr] : -1;
      wS[tid]   = v ? slot_weight[seg + lr] : 0.f;
    }
    __syncthreads();
#pragma unroll
    for (int mi = 0; mi < 4; ++mi) {
#pragma unroll
      for (int i = 0; i < 4; ++i) {
        const int rl = wm * 64 + mi * 16 + quad * 4 + i;
        const int tok = tokS[rl];
        if (tok < 0) continue;
        const float wgt = wS[rl];
        float* orow = out + (size_t)tok * H_DIM + n0 + wn * 64 + l16;
#pragma unroll
        for (int ni = 0; ni < 4; ++ni)
          atomicAdd(orow + ni * 16, wgt * acc[mi][ni][i]);
      }
    }
  }
}

// ---------------- workspace layout (bytes) ----------------
#define OFF_XBF  ((size_t)0)                       // 33,554,432  x_bf [T][H] bf16
#define OFF_W1T  ((size_t)33554432)                // 33,554,432  w1t [DFF][H] bf16 (current expert)
#define OFF_W2T  ((size_t)67108864)                // 33,554,432  w2t [H][DFF] bf16 (current expert)
#define OFF_HMID ((size_t)100663296)               // 142,606,336 hmid chunk [CHUNK][DFF] bf16
#define OFF_META ((size_t)243269632)
// meta: counts@0(32B) seg_off@64 cursors@128 | topk_idx@512 topk_w@+64K slot_tok@+128K slot_w@+192K

extern "C" void kernel_launch(void* const* d_in, const int* in_sizes, int n_in,
                              void* d_out, int out_size, void* d_ws, size_t ws_size,
                              hipStream_t stream)
{
  const float* x  = (const float*)d_in[0];
  const float* wg = (const float*)d_in[1];
  const float* w1 = (const float*)d_in[2];
  const float* w2 = (const float*)d_in[3];

  float* out    = (float*)d_out;                       // [T][H]
  float* logits = out + (size_t)T_TOK * H_DIM;         // [T][E]

  char* ws = (char*)d_ws;
  unsigned short* x_bf = (unsigned short*)(ws + OFF_XBF);
  unsigned short* w1t  = (unsigned short*)(ws + OFF_W1T);
  unsigned short* w2t  = (unsigned short*)(ws + OFF_W2T);
  unsigned short* hmid = (unsigned short*)(ws + OFF_HMID);
  char* meta = ws + OFF_META;
  int*   counts      = (int*)(meta);
  int*   seg_off     = (int*)(meta + 64);
  int*   cursors     = (int*)(meta + 128);
  int*   topk_idx    = (int*)(meta + 512);
  float* topk_w      = (float*)(meta + 512 + 65536);
  int*   slot_token  = (int*)(meta + 512 + 131072);
  float* slot_weight = (float*)(meta + 512 + 196608);

  hipMemsetAsync(out, 0, (size_t)T_TOK * H_DIM * sizeof(float), stream);
  hipMemsetAsync(counts, 0, 32, stream);

  router_kernel<<<T_TOK, 64, 0, stream>>>(x, wg, logits, x_bf, topk_idx, topk_w, counts);
  scan_kernel<<<1, 64, 0, stream>>>(counts, seg_off, cursors);
  scatter_kernel<<<(T_TOK * 2 + 255) / 256, 256, 0, stream>>>(topk_idx, topk_w, cursors,
                                                              slot_token, slot_weight);

  for (int e = 0; e < NEXP; ++e) {
    const float* w1e = w1 + (size_t)e * H_DIM * DFF_D;   // [H][DFF]
    const float* w2e = w2 + (size_t)e * H_DIM * DFF_D;   // [DFF][H]
    transpose_cvt<<<dim3(DFF_D / 64, H_DIM / 64), 256, 0, stream>>>(w1e, w1t, H_DIM, DFF_D);
    transpose_cvt<<<dim3(H_DIM / 64, DFF_D / 64), 256, 0, stream>>>(w2e, w2t, DFF_D, H_DIM);
    for (int c = 0; c < 2; ++c) {
      moe_gemm<H_DIM, 0><<<dim3(CHUNK / BM, DFF_D / BN), 256, 0, stream>>>(
          x_bf, w1t, hmid, nullptr, counts, seg_off, slot_token, slot_weight, e, c);
      moe_gemm<DFF_D, 1><<<dim3(CHUNK / BM, H_DIM / BN), 256, 0, stream>>>(
          hmid, w2t, nullptr, out, counts, seg_off, slot_token, slot_weight, e, c);
    }
  }
}